// Round 1
// baseline (3320.981 us; speedup 1.0000x reference)
//
#include <hip/hip_runtime.h>
#include <hip/hip_bf16.h>
#include <cstdint>

#define S_LEN 2048
#define HIDDEN 2560
#define NH 32
#define NKV 8
#define HD 128
#define GS 128

// ---------------------------------------------------------------------------
// Fused dequant (AWQ int4) GEMM:  Y[M][N] = X[M][K] @ dequant(QW,SC,QZ) + bias
// qweight: [K/8][N] int32, nibble j of word k8 is w[k8*8+j][n]
// w = (nibble - zero) * scale, group = k / GS
// Tiling: BM = 16*TM, BN = 128, BK = 64; 256 threads; TMx8 per-thread tile.
// ---------------------------------------------------------------------------
template <int TM>
__global__ __launch_bounds__(256) void qgemm_kernel(
    const float* __restrict__ X, const int* __restrict__ QW,
    const float* __restrict__ SC, const int* __restrict__ QZ,
    const float* __restrict__ bias, float* __restrict__ Y,
    int M, int K, int N)
{
    constexpr int BM = 16 * TM;
    constexpr int BN = 128;
    constexpr int BK = 64;
    __shared__ float Xs[BM][BK];
    __shared__ float Ws[BK][BN];

    const int t  = threadIdx.x;
    const int tx = t & 15;
    const int ty = t >> 4;
    const int n0 = blockIdx.x * BN;
    const int m0 = blockIdx.y * BM;

    float acc[TM][8];
#pragma unroll
    for (int i = 0; i < TM; ++i)
#pragma unroll
        for (int j = 0; j < 8; ++j) acc[i][j] = 0.f;

    for (int k0 = 0; k0 < K; k0 += BK) {
        // ---- stage X tile (coalesced float4) ----
#pragma unroll
        for (int i = 0; i < TM; ++i) {
            int r = i * 16 + ty;
            *(float4*)&Xs[r][tx * 4] =
                *(const float4*)&X[(size_t)(m0 + r) * K + k0 + tx * 4];
        }
        // ---- stage + dequant W tile ----
        // BK=64 spans one quant group (since 64 | GS=128 and k0 % 64 == 0)
        const int g = k0 / GS;
#pragma unroll
        for (int i = 0; i < 4; ++i) {
            int idx  = t + 256 * i;       // 0..1023 over 8 krows x 128 cols
            int krow = idx >> 7;          // 0..7
            int n    = idx & 127;
            uint32_t qw = (uint32_t)QW[(size_t)(k0 / 8 + krow) * N + n0 + n];
            float sc = SC[(size_t)g * N + n0 + n];
            float zf = (float)QZ[(size_t)g * N + n0 + n];
#pragma unroll
            for (int j = 0; j < 8; ++j) {
                Ws[krow * 8 + j][n] = ((float)((qw >> (4 * j)) & 15u) - zf) * sc;
            }
        }
        __syncthreads();

#pragma unroll 4
        for (int kk = 0; kk < BK; ++kk) {
            float4 b0 = *(const float4*)&Ws[kk][tx * 8];
            float4 b1 = *(const float4*)&Ws[kk][tx * 8 + 4];
#pragma unroll
            for (int i = 0; i < TM; ++i) {
                float a = Xs[i * 16 + ty][kk];
                acc[i][0] += a * b0.x; acc[i][1] += a * b0.y;
                acc[i][2] += a * b0.z; acc[i][3] += a * b0.w;
                acc[i][4] += a * b1.x; acc[i][5] += a * b1.y;
                acc[i][6] += a * b1.z; acc[i][7] += a * b1.w;
            }
        }
        __syncthreads();
    }

    // ---- epilogue ----
#pragma unroll
    for (int i = 0; i < TM; ++i) {
        int row = m0 + i * 16 + ty;
        float* yp = &Y[(size_t)row * N + n0 + tx * 8];
        float4 o0, o1;
        o0.x = acc[i][0]; o0.y = acc[i][1]; o0.z = acc[i][2]; o0.w = acc[i][3];
        o1.x = acc[i][4]; o1.y = acc[i][5]; o1.z = acc[i][6]; o1.w = acc[i][7];
        if (bias) {
            const float* bp = &bias[n0 + tx * 8];
            o0.x += bp[0]; o0.y += bp[1]; o0.z += bp[2]; o0.w += bp[3];
            o1.x += bp[4]; o1.y += bp[5]; o1.z += bp[6]; o1.w += bp[7];
        }
        *(float4*)yp = o0;
        *(float4*)(yp + 4) = o1;
    }
}

// ---------------------------------------------------------------------------
// RoPE in-place on Q [S][NH*HD] and K [S][NKV*HD].
// out[d]    = x[d]*cos[d]   - x[d+64]*sin[d]
// out[d+64] = x[d+64]*cos[d] + x[d]*sin[d]      (cos/sin repeat at +64)
// ---------------------------------------------------------------------------
__global__ __launch_bounds__(256) void rope_kernel(
    float* __restrict__ Q, float* __restrict__ Kb,
    const float* __restrict__ cosb, const float* __restrict__ sinb)
{
    const int QP = S_LEN * NH * 64;   // 4194304 q pairs
    const int KP = S_LEN * NKV * 64;  // 1048576 k pairs
    int idx = blockIdx.x * 256 + threadIdx.x;
    float* buf;
    int nh, id;
    if (idx < QP)            { buf = Q;  nh = NH;  id = idx; }
    else if (idx < QP + KP)  { buf = Kb; nh = NKV; id = idx - QP; }
    else return;
    int d  = id & 63;
    int t2 = id >> 6;
    int h  = t2 % nh;
    int s  = t2 / nh;
    float c  = cosb[s * HD + d];
    float sn = sinb[s * HD + d];
    size_t base = (size_t)s * nh * HD + h * HD + d;
    float x1 = buf[base];
    float x2 = buf[base + 64];
    buf[base]      = x1 * c - x2 * sn;
    buf[base + 64] = x2 * c + x1 * sn;
}

// ---------------------------------------------------------------------------
// Causal GQA flash attention (fp32 vector baseline).
// One WG = (head h, 64 q-rows). 256 threads: thread = (qr = t>>2, c = t&3),
// each owns dims [c*32, c*32+32) of one q row. Online softmax over 32-row
// K/V tiles staged in LDS. Causality: only tiles with k0 <= qg processed.
// ---------------------------------------------------------------------------
#define QT 64
#define KT 32

__global__ __launch_bounds__(256) void attn_kernel(
    const float* __restrict__ Q,   // [S][NH*HD]  (roped)
    const float* __restrict__ K,   // [S][NKV*HD] (roped)
    const float* __restrict__ V,   // [S][NKV*HD]
    float* __restrict__ AO)        // [S][NH*HD]
{
    __shared__ float Ks[KT][HD];
    __shared__ float Vs[KT][HD];

    const int h   = blockIdx.x;        // 0..31
    const int s0  = blockIdx.y * QT;
    const int t   = threadIdx.x;
    const int qr  = t >> 2;
    const int c   = t & 3;
    const int kvh = h >> 2;            // GQA: 4 q-heads per kv-head
    const int qg  = s0 + qr;

    const float scale = 0.08838834764831845f;  // 1/sqrt(128)

    float Qr[32];
    {
        const float* qrow = Q + (size_t)qg * (NH * HD) + h * HD + c * 32;
#pragma unroll
        for (int j = 0; j < 32; j += 4) {
            float4 v = *(const float4*)(qrow + j);
            Qr[j] = v.x * scale; Qr[j + 1] = v.y * scale;
            Qr[j + 2] = v.z * scale; Qr[j + 3] = v.w * scale;
        }
    }
    float Ob[32];
#pragma unroll
    for (int j = 0; j < 32; ++j) Ob[j] = 0.f;
    float m = -1e30f, l = 0.f;

    const int ntiles = s0 / KT + 2;   // covers k <= s0 + QT - 1
    for (int kt = 0; kt < ntiles; ++kt) {
        const int k0 = kt * KT;
        // stage K/V tile: 32 rows x 128 dims each
#pragma unroll
        for (int i = 0; i < 4; ++i) {
            int e   = t + 256 * i;      // float4 units, 0..1023
            int row = e >> 5;
            int col = (e & 31) * 4;
            *(float4*)&Ks[row][col] =
                *(const float4*)&K[(size_t)(k0 + row) * (NKV * HD) + kvh * HD + col];
            *(float4*)&Vs[row][col] =
                *(const float4*)&V[(size_t)(k0 + row) * (NKV * HD) + kvh * HD + col];
        }
        __syncthreads();

        float sv[KT];
#pragma unroll
        for (int k = 0; k < KT; ++k) {
            float su = 0.f;
#pragma unroll
            for (int j = 0; j < 32; j += 4) {
                float4 kv = *(const float4*)&Ks[k][c * 32 + j];
                su += Qr[j] * kv.x + Qr[j + 1] * kv.y +
                      Qr[j + 2] * kv.z + Qr[j + 3] * kv.w;
            }
            su += __shfl_xor(su, 1);
            su += __shfl_xor(su, 2);
            sv[k] = (k0 + k <= qg) ? su : -1e30f;
        }
        float tm = m;
#pragma unroll
        for (int k = 0; k < KT; ++k) tm = fmaxf(tm, sv[k]);
        float resc = __expf(m - tm);   // tile0 always has a valid k -> tm finite
        m = tm;
        float lsum = 0.f;
#pragma unroll
        for (int k = 0; k < KT; ++k) { sv[k] = __expf(sv[k] - m); lsum += sv[k]; }
        l = l * resc + lsum;
#pragma unroll
        for (int j = 0; j < 32; ++j) Ob[j] *= resc;
#pragma unroll
        for (int k = 0; k < KT; ++k) {
            float p = sv[k];
#pragma unroll
            for (int j = 0; j < 32; j += 4) {
                float4 vv = *(const float4*)&Vs[k][c * 32 + j];
                Ob[j] += p * vv.x; Ob[j + 1] += p * vv.y;
                Ob[j + 2] += p * vv.z; Ob[j + 3] += p * vv.w;
            }
        }
        __syncthreads();
    }

    float inv = 1.f / l;
    float* orow = AO + (size_t)qg * (NH * HD) + h * HD + c * 32;
#pragma unroll
    for (int j = 0; j < 32; j += 4) {
        float4 v;
        v.x = Ob[j] * inv; v.y = Ob[j + 1] * inv;
        v.z = Ob[j + 2] * inv; v.w = Ob[j + 3] * inv;
        *(float4*)(orow + j) = v;
    }
}

// ---------------------------------------------------------------------------
extern "C" void kernel_launch(void* const* d_in, const int* in_sizes, int n_in,
                              void* d_out, int out_size, void* d_ws, size_t ws_size,
                              hipStream_t stream)
{
    const float* x    = (const float*)d_in[0];
    const float* cosb = (const float*)d_in[1];
    const float* sinb = (const float*)d_in[2];
    const float* q_sc = (const float*)d_in[3];
    const float* q_b  = (const float*)d_in[4];
    const float* k_sc = (const float*)d_in[5];
    const float* k_b  = (const float*)d_in[6];
    const float* v_sc = (const float*)d_in[7];
    const float* v_b  = (const float*)d_in[8];
    const float* o_sc = (const float*)d_in[9];
    const int* q_qw   = (const int*)d_in[10];
    const int* q_qz   = (const int*)d_in[11];
    const int* k_qw   = (const int*)d_in[12];
    const int* k_qz   = (const int*)d_in[13];
    const int* v_qw   = (const int*)d_in[14];
    const int* v_qz   = (const int*)d_in[15];
    const int* o_qw   = (const int*)d_in[16];
    const int* o_qz   = (const int*)d_in[17];
    float* out = (float*)d_out;

    // workspace layout (fp32): Q[2048][4096] K[2048][1024] V[2048][1024] AO[2048][4096]
    float* ws = (float*)d_ws;
    float* Qb = ws;
    float* Kb = Qb + (size_t)S_LEN * (NH * HD);
    float* Vb = Kb + (size_t)S_LEN * (NKV * HD);
    float* AO = Vb + (size_t)S_LEN * (NKV * HD);

    // Q/K/V projections (fused dequant GEMM + bias)
    qgemm_kernel<8><<<dim3(4096 / 128, 2048 / 128), 256, 0, stream>>>(
        x, q_qw, q_sc, q_qz, q_b, Qb, S_LEN, HIDDEN, NH * HD);
    qgemm_kernel<4><<<dim3(1024 / 128, 2048 / 64), 256, 0, stream>>>(
        x, k_qw, k_sc, k_qz, k_b, Kb, S_LEN, HIDDEN, NKV * HD);
    qgemm_kernel<4><<<dim3(1024 / 128, 2048 / 64), 256, 0, stream>>>(
        x, v_qw, v_sc, v_qz, v_b, Vb, S_LEN, HIDDEN, NKV * HD);

    // RoPE in-place on Q and K
    rope_kernel<<<(S_LEN * NH * 64 + S_LEN * NKV * 64) / 256, 256, 0, stream>>>(
        Qb, Kb, cosb, sinb);

    // causal GQA attention
    attn_kernel<<<dim3(NH, S_LEN / QT), 256, 0, stream>>>(Qb, Kb, Vb, AO);

    // output projection (no bias)
    qgemm_kernel<8><<<dim3(2560 / 128, 2048 / 128), 256, 0, stream>>>(
        AO, o_qw, o_sc, o_qz, nullptr, out, S_LEN, NH * HD, HIDDEN);
}

// Round 3
// 1785.897 us; speedup vs baseline: 1.8596x; 1.8596x over previous
//
#include <hip/hip_runtime.h>
#include <hip/hip_bf16.h>
#include <cstdint>

#define S_LEN 2048
#define HIDDEN 2560
#define NH 32
#define NKV 8
#define HD 128
#define GS 128

typedef __attribute__((ext_vector_type(8))) short short8v;  // 8 x bf16 frag
typedef __attribute__((ext_vector_type(4))) float f32x4;
typedef unsigned int uint;
typedef unsigned short ushort;

__device__ inline ushort f2bf(float f) {
    uint u = __builtin_bit_cast(uint, f);
    u += 0x7fffu + ((u >> 16) & 1u);   // RNE
    return (ushort)(u >> 16);
}
__device__ inline float bf2f(ushort u) {
    return __builtin_bit_cast(float, (uint)u << 16);
}

// ---------------------------------------------------------------------------
// Fused dequant (AWQ int4) GEMM:  Y[M][N] = X[M][K] @ dequant(QW,SC,QZ) + bias
// OMODE: 0 = fp32 row-major (bias optional)
//        2 = bf16 TRANSPOSED [N][M] (+bias)
//        4 = fp32 row-major, +bias, RoPE fused (BN==HD, head-aligned), *oscale
// XBF:   0 = X is fp32, 1 = X is bf16
// ---------------------------------------------------------------------------
template <int TM, int OMODE, int XBF>
__global__ __launch_bounds__(256) void qgemm_kernel(
    const void* __restrict__ Xv, const int* __restrict__ QW,
    const float* __restrict__ SC, const int* __restrict__ QZ,
    const float* __restrict__ bias, void* __restrict__ Yv,
    const float* __restrict__ cosb, const float* __restrict__ sinb,
    float oscale, int M, int K, int N)
{
    constexpr int BM = 16 * TM;
    constexpr int BN = 128;
    constexpr int BK = 64;
    __shared__ float Xs[BM][BK];
    __shared__ float Ws[BK][BN];

    const int t  = threadIdx.x;
    const int tx = t & 15;
    const int ty = t >> 4;
    const int n0 = blockIdx.x * BN;
    const int m0 = blockIdx.y * BM;

    float acc[TM][8];
#pragma unroll
    for (int i = 0; i < TM; ++i)
#pragma unroll
        for (int j = 0; j < 8; ++j) acc[i][j] = 0.f;

    for (int k0 = 0; k0 < K; k0 += BK) {
        // ---- stage X tile ----
#pragma unroll
        for (int i = 0; i < TM; ++i) {
            int r = i * 16 + ty;
            if constexpr (XBF == 0) {
                *(float4*)&Xs[r][tx * 4] =
                    *(const float4*)&((const float*)Xv)[(size_t)(m0 + r) * K + k0 + tx * 4];
            } else {
                uint2 u = *(const uint2*)&((const ushort*)Xv)[(size_t)(m0 + r) * K + k0 + tx * 4];
                float4 f;
                f.x = bf2f((ushort)(u.x & 0xffff));
                f.y = bf2f((ushort)(u.x >> 16));
                f.z = bf2f((ushort)(u.y & 0xffff));
                f.w = bf2f((ushort)(u.y >> 16));
                *(float4*)&Xs[r][tx * 4] = f;
            }
        }
        // ---- stage + dequant W tile ----
        const int g = k0 / GS;
#pragma unroll
        for (int i = 0; i < 4; ++i) {
            int idx  = t + 256 * i;
            int krow = idx >> 7;
            int n    = idx & 127;
            uint32_t qw = (uint32_t)QW[(size_t)(k0 / 8 + krow) * N + n0 + n];
            float sc = SC[(size_t)g * N + n0 + n];
            float zf = (float)QZ[(size_t)g * N + n0 + n];
#pragma unroll
            for (int j = 0; j < 8; ++j) {
                Ws[krow * 8 + j][n] = ((float)((qw >> (4 * j)) & 15u) - zf) * sc;
            }
        }
        __syncthreads();

#pragma unroll 4
        for (int kk = 0; kk < BK; ++kk) {
            float4 b0 = *(const float4*)&Ws[kk][tx * 8];
            float4 b1 = *(const float4*)&Ws[kk][tx * 8 + 4];
#pragma unroll
            for (int i = 0; i < TM; ++i) {
                float a = Xs[i * 16 + ty][kk];
                acc[i][0] += a * b0.x; acc[i][1] += a * b0.y;
                acc[i][2] += a * b0.z; acc[i][3] += a * b0.w;
                acc[i][4] += a * b1.x; acc[i][5] += a * b1.y;
                acc[i][6] += a * b1.z; acc[i][7] += a * b1.w;
            }
        }
        __syncthreads();
    }

    // ---- epilogue ----
#pragma unroll
    for (int i = 0; i < TM; ++i) {
        int row = m0 + i * 16 + ty;
        float v[8];
#pragma unroll
        for (int j = 0; j < 8; ++j) v[j] = acc[i][j];
        if (OMODE != 0 || bias) {
            const float* bp = &bias[n0 + tx * 8];
#pragma unroll
            for (int j = 0; j < 8; ++j) v[j] += bp[j];
        }
        if constexpr (OMODE == 0) {
            float* yp = &((float*)Yv)[(size_t)row * N + n0 + tx * 8];
            float4 o0 = {v[0], v[1], v[2], v[3]};
            float4 o1 = {v[4], v[5], v[6], v[7]};
            *(float4*)yp = o0;
            *(float4*)(yp + 4) = o1;
        } else if constexpr (OMODE == 2) {
            ushort* yt = (ushort*)Yv;
#pragma unroll
            for (int j = 0; j < 8; ++j)
                yt[(size_t)(n0 + tx * 8 + j) * M + row] = f2bf(v[j]);
        } else {
            // RoPE in fp32: d = tx*8+j within head (BN == HD, n0 head-aligned).
            // partner dim d^64 lives in lane tx^8 (same wave), same j.
            float vr[8];
#pragma unroll
            for (int j = 0; j < 8; ++j) {
                int d = tx * 8 + j;
                float c  = cosb[(size_t)row * HD + d];
                float sn = sinb[(size_t)row * HD + d];
                float p  = __shfl_xor(v[j], 8);
                float r2 = (tx < 8) ? (v[j] * c - p * sn) : (v[j] * c + p * sn);
                vr[j] = r2 * oscale;
            }
            float* yp = &((float*)Yv)[(size_t)row * N + n0 + tx * 8];
            float4 o0 = {vr[0], vr[1], vr[2], vr[3]};
            float4 o1 = {vr[4], vr[5], vr[6], vr[7]};
            *(float4*)yp = o0;
            *(float4*)(yp + 4) = o1;
        }
    }
}

// ---------------------------------------------------------------------------
// Causal GQA flash attention, bf16 MFMA (16x16x32), compensated hi/lo QK^T.
// Block = (head, 64 q rows), 4 waves, wave w owns q rows qw = s0+16w.
// Q, K fp32 in (roped, Q pre-scaled); scores S = qhi*khi + qlo*khi + qhi*klo
// are fp32-accurate. V bf16 transposed; P bf16 via swizzled LDS round-trip.
// MFMA layouts (m89/m92-verified): A/B lane l -> index l&15, k=(l>>4)*8+i;
// C/D: col=l&15, row=(l>>4)*4+reg.
// ---------------------------------------------------------------------------
__global__ __launch_bounds__(256) void attn_mfma_kernel(
    const float*  __restrict__ Q,    // [S][NH*HD] f32, roped, * 1/sqrt(HD)
    const float*  __restrict__ K,    // [S][NKV*HD] f32, roped
    const ushort* __restrict__ Vt,   // [NKV*HD][S] bf16 (transposed)
    ushort* __restrict__ AO)         // [S][NH*HD] bf16
{
    __shared__ ushort Khi[32 * 128];      // 8 KB, swz byte^=((row&7)<<4)
    __shared__ ushort Klo[32 * 128];      // 8 KB
    __shared__ ushort Vs[128 * 32];       // 8 KB, swz byte^=((dim&3)<<4)
    __shared__ ushort Ps[4][16 * 32];     // 4 KB, swz byte^=((row&3)<<4)

    const int h  = blockIdx.x;
    const int qb = gridDim.y - 1 - blockIdx.y;   // long blocks dispatch first
    const int s0 = qb * 64;
    const int t  = threadIdx.x;
    const int w  = t >> 6;
    const int l  = t & 63;
    const int lg = l >> 4;      // 0..3
    const int lr = l & 15;      // 0..15
    const int kvh = h >> 2;
    const int qw = s0 + w * 16;

    // Q fragments hi/lo: dims d*32 + lg*8 .. +8 of q-row qw+lr
    short8v qhi[4], qlo[4];
    {
        const float* qrow = &Q[(size_t)(qw + lr) * (NH * HD) + h * HD];
#pragma unroll
        for (int d = 0; d < 4; ++d) {
            float4 a = *(const float4*)(qrow + d * 32 + lg * 8);
            float4 b = *(const float4*)(qrow + d * 32 + lg * 8 + 4);
            float qv[8] = {a.x, a.y, a.z, a.w, b.x, b.y, b.z, b.w};
#pragma unroll
            for (int i2 = 0; i2 < 8; ++i2) {
                ushort hi = f2bf(qv[i2]);
                qhi[d][i2] = (short)hi;
                qlo[d][i2] = (short)f2bf(qv[i2] - bf2f(hi));
            }
        }
    }

    f32x4 o[8];
#pragma unroll
    for (int i = 0; i < 8; ++i) o[i] = f32x4{0.f, 0.f, 0.f, 0.f};
    float m[4], lsum[4];
#pragma unroll
    for (int r = 0; r < 4; ++r) { m[r] = -1e30f; lsum[r] = 0.f; }

    const int ntiles = qb * 2 + 2;
    for (int kt = 0; kt < ntiles; ++kt) {
        const int k0 = kt * 32;
        // ---- stage K tile f32 -> hi/lo bf16, swizzled ----
#pragma unroll
        for (int i = 0; i < 4; ++i) {
            int e   = t + 256 * i;     // float4 units, 0..1023
            int row = e >> 5;
            int c4  = e & 31;
            float4 kv = *(const float4*)&K[(size_t)(k0 + row) * (NKV * HD) + kvh * HD + c4 * 4];
            ushort h0 = f2bf(kv.x), h1 = f2bf(kv.y), h2 = f2bf(kv.z), h3 = f2bf(kv.w);
            uint2 hw, lw;
            hw.x = (uint)h0 | ((uint)h1 << 16);
            hw.y = (uint)h2 | ((uint)h3 << 16);
            lw.x = (uint)f2bf(kv.x - bf2f(h0)) | ((uint)f2bf(kv.y - bf2f(h1)) << 16);
            lw.y = (uint)f2bf(kv.z - bf2f(h2)) | ((uint)f2bf(kv.w - bf2f(h3)) << 16);
            int off = row * 256 + ((c4 * 8) ^ ((row & 7) << 4));
            *(uint2*)((char*)Khi + off) = hw;
            *(uint2*)((char*)Klo + off) = lw;
        }
        // ---- stage V^T tile ----
        {
            int d = t & 127, g2 = t >> 7;
            const ushort* src = &Vt[(size_t)(kvh * HD + d) * S_LEN + k0 + g2 * 16];
            uint4 v0 = *(const uint4*)src;
            uint4 v1 = *(const uint4*)(src + 8);
            char* base = (char*)Vs + d * 64;
            *(uint4*)(base + ((g2 * 32)      ^ ((d & 3) << 4))) = v0;
            *(uint4*)(base + ((g2 * 32 + 16) ^ ((d & 3) << 4))) = v1;
        }
        __syncthreads();

        if (k0 <= qw + 15) {   // wave-uniform causal skip
            // ---- S = Q K^T (compensated) ----
            f32x4 s[2];
            s[0] = f32x4{0.f, 0.f, 0.f, 0.f};
            s[1] = f32x4{0.f, 0.f, 0.f, 0.f};
#pragma unroll
            for (int d = 0; d < 4; ++d) {
#pragma unroll
                for (int nt2 = 0; nt2 < 2; ++nt2) {
                    int row = nt2 * 16 + lr;
                    int off = row * 256 + ((d * 64 + lg * 16) ^ ((row & 7) << 4));
                    short8v kh = *(const short8v*)((char*)Khi + off);
                    short8v kl = *(const short8v*)((char*)Klo + off);
                    s[nt2] = __builtin_amdgcn_mfma_f32_16x16x32_bf16(qhi[d], kh, s[nt2], 0, 0, 0);
                    s[nt2] = __builtin_amdgcn_mfma_f32_16x16x32_bf16(qlo[d], kh, s[nt2], 0, 0, 0);
                    s[nt2] = __builtin_amdgcn_mfma_f32_16x16x32_bf16(qhi[d], kl, s[nt2], 0, 0, 0);
                }
            }
            // ---- mask + online softmax (per reg = q-row) ----
            float p0a[4], p1a[4], resc[4];
#pragma unroll
            for (int r = 0; r < 4; ++r) {
                int qrow = qw + lg * 4 + r;
                float s0v = (k0 + lr      <= qrow) ? s[0][r] : -1e30f;
                float s1v = (k0 + 16 + lr <= qrow) ? s[1][r] : -1e30f;
                float mx = fmaxf(s0v, s1v);
                mx = fmaxf(mx, __shfl_xor(mx, 1));
                mx = fmaxf(mx, __shfl_xor(mx, 2));
                mx = fmaxf(mx, __shfl_xor(mx, 4));
                mx = fmaxf(mx, __shfl_xor(mx, 8));
                float mnew = fmaxf(m[r], mx);
                resc[r] = __expf(m[r] - mnew);
                m[r] = mnew;
                float p0 = __expf(s0v - mnew);
                float p1 = __expf(s1v - mnew);
                p0a[r] = p0; p1a[r] = p1;
                float ps = p0 + p1;
                ps += __shfl_xor(ps, 1);
                ps += __shfl_xor(ps, 2);
                ps += __shfl_xor(ps, 4);
                ps += __shfl_xor(ps, 8);
                lsum[r] = lsum[r] * resc[r] + ps;
            }
            // ---- rescale O ----
#pragma unroll
            for (int dt = 0; dt < 8; ++dt)
#pragma unroll
                for (int r = 0; r < 4; ++r) o[dt][r] *= resc[r];
            // ---- P -> LDS (bf16, swizzled), C-layout -> A-layout ----
            ushort* pw = Ps[w];
#pragma unroll
            for (int r = 0; r < 4; ++r) {
                int row = lg * 4 + r;
                *(ushort*)((char*)pw + row * 64 + (((lr)      * 2) ^ ((row & 3) << 4))) = f2bf(p0a[r]);
                *(ushort*)((char*)pw + row * 64 + (((lr + 16) * 2) ^ ((row & 3) << 4))) = f2bf(p1a[r]);
            }
            asm volatile("s_waitcnt lgkmcnt(0)" ::: "memory");
            short8v pf = *(const short8v*)((char*)pw + lr * 64 + ((lg * 16) ^ ((lr & 3) << 4)));
            // ---- O += P V ----
#pragma unroll
            for (int dt = 0; dt < 8; ++dt) {
                int dim = dt * 16 + lr;
                short8v vf = *(const short8v*)((char*)Vs + dim * 64 + ((lg * 16) ^ ((dim & 3) << 4)));
                o[dt] = __builtin_amdgcn_mfma_f32_16x16x32_bf16(pf, vf, o[dt], 0, 0, 0);
            }
        }
        __syncthreads();
    }

    // ---- epilogue: normalize + store bf16 ----
#pragma unroll
    for (int r = 0; r < 4; ++r) {
        float inv = 1.f / lsum[r];
        int qrow = qw + lg * 4 + r;
        ushort* dst = &AO[(size_t)qrow * (NH * HD) + h * HD];
#pragma unroll
        for (int dt = 0; dt < 8; ++dt) dst[dt * 16 + lr] = f2bf(o[dt][r] * inv);
    }
}

// ---------------------------------------------------------------------------
extern "C" void kernel_launch(void* const* d_in, const int* in_sizes, int n_in,
                              void* d_out, int out_size, void* d_ws, size_t ws_size,
                              hipStream_t stream)
{
    const float* x    = (const float*)d_in[0];
    const float* cosb = (const float*)d_in[1];
    const float* sinb = (const float*)d_in[2];
    const float* q_sc = (const float*)d_in[3];
    const float* q_b  = (const float*)d_in[4];
    const float* k_sc = (const float*)d_in[5];
    const float* k_b  = (const float*)d_in[6];
    const float* v_sc = (const float*)d_in[7];
    const float* v_b  = (const float*)d_in[8];
    const float* o_sc = (const float*)d_in[9];
    const int* q_qw   = (const int*)d_in[10];
    const int* q_qz   = (const int*)d_in[11];
    const int* k_qw   = (const int*)d_in[12];
    const int* k_qz   = (const int*)d_in[13];
    const int* v_qw   = (const int*)d_in[14];
    const int* v_qz   = (const int*)d_in[15];
    const int* o_qw   = (const int*)d_in[16];
    const int* o_qz   = (const int*)d_in[17];
    float* out = (float*)d_out;

    // ws: Qf32 32MB | Kf32 8MB | VbfT 4MB | AObf16 16MB  = 60MB
    char* ws = (char*)d_ws;
    float*  Qf   = (float*)ws;
    float*  Kf   = (float*)(ws + (size_t)32 * 1024 * 1024);
    ushort* VbfT = (ushort*)(ws + (size_t)40 * 1024 * 1024);
    ushort* AObf = (ushort*)(ws + (size_t)44 * 1024 * 1024);

    const float qscale = 0.08838834764831845f;  // 1/sqrt(128)

    qgemm_kernel<8, 4, 0><<<dim3(NH * HD / 128, S_LEN / 128), 256, 0, stream>>>(
        x, q_qw, q_sc, q_qz, q_b, Qf, cosb, sinb, qscale, S_LEN, HIDDEN, NH * HD);
    qgemm_kernel<4, 4, 0><<<dim3(NKV * HD / 128, S_LEN / 64), 256, 0, stream>>>(
        x, k_qw, k_sc, k_qz, k_b, Kf, cosb, sinb, 1.0f, S_LEN, HIDDEN, NKV * HD);
    qgemm_kernel<4, 2, 0><<<dim3(NKV * HD / 128, S_LEN / 64), 256, 0, stream>>>(
        x, v_qw, v_sc, v_qz, v_b, VbfT, nullptr, nullptr, 1.0f, S_LEN, HIDDEN, NKV * HD);

    attn_mfma_kernel<<<dim3(NH, S_LEN / 64), 256, 0, stream>>>(Qf, Kf, VbfT, AObf);

    qgemm_kernel<8, 0, 1><<<dim3(HIDDEN / 128, S_LEN / 128), 256, 0, stream>>>(
        AObf, o_qw, o_sc, o_qz, nullptr, out, nullptr, nullptr, 1.0f, S_LEN, NH * HD, HIDDEN);
}

// Round 4
// 907.146 us; speedup vs baseline: 3.6609x; 1.9687x over previous
//
#include <hip/hip_runtime.h>
#include <hip/hip_bf16.h>
#include <cstdint>

#define S_LEN 2048
#define HIDDEN 2560
#define NH 32
#define NKV 8
#define HD 128
#define GS 128

typedef __attribute__((ext_vector_type(8))) short short8v;  // 8 x bf16 frag
typedef __attribute__((ext_vector_type(4))) float f32x4;
typedef unsigned int uint;
typedef unsigned short ushort;

__device__ inline ushort f2bf(float f) {
    uint u = __builtin_bit_cast(uint, f);
    u += 0x7fffu + ((u >> 16) & 1u);   // RNE
    return (ushort)(u >> 16);
}
__device__ inline float bf2f(ushort u) {
    return __builtin_bit_cast(float, (uint)u << 16);
}
__device__ inline uint pk2(ushort a, ushort b) { return (uint)a | ((uint)b << 16); }

// ---------------------------------------------------------------------------
// MFMA AWQ-int4 GEMM:  Y[M][N] = X[M][K] @ ((nib - z) * sc) (+ bias)
// Numerics: B-tile = (nib - z) is EXACT in bf16 (small ints). Per-group
// partials accumulate in fp32 MFMA, then macc += sc * gacc (fp32). The only
// rounding is X's bf16 cast; XMODE 0 compensates with hi/lo (2 MFMA).
//   XMODE: 0 = f32 X, hi/lo compensated; 1 = f32 X, hi only; 2 = bf16 X
//   OMODE: 0 = f32 row-major (+bias if nonnull); 2 = bf16 transposed [N][M]
// Tile: BM=128 BN=128 BK=64, 4 waves, wave w owns rows [w*32, w*32+32).
// LDS swizzle (G4): byte ^= ((row & 7) << 4) within each 128B row.
// ---------------------------------------------------------------------------
template <int XMODE, int OMODE>
__global__ __launch_bounds__(256) void qgemm_mfma_kernel(
    const void* __restrict__ Xv, const int* __restrict__ QW,
    const float* __restrict__ SC, const int* __restrict__ QZ,
    const float* __restrict__ bias, void* __restrict__ Yv,
    int M, int K, int N)
{
    constexpr bool HILO = (XMODE == 0);
    __shared__ ushort Ahi[128 * 64];                       // 16 KB
    __shared__ ushort Alo[HILO ? 128 * 64 : 64];           // 16 KB if hi/lo
    __shared__ ushort Bt[128 * 64];                        // 16 KB, [n][k]

    const int t  = threadIdx.x;
    const int w  = t >> 6;
    const int l  = t & 63;
    const int lg = l >> 4;
    const int lr = l & 15;
    const int n0 = blockIdx.x * 128;
    const int m0 = blockIdx.y * 128;

    f32x4 macc[2][8];
#pragma unroll
    for (int mf = 0; mf < 2; ++mf)
#pragma unroll
        for (int nf = 0; nf < 8; ++nf) macc[mf][nf] = f32x4{0.f, 0.f, 0.f, 0.f};
    f32x4 gacc[2][8];
    const f32x4 zc = f32x4{0.f, 0.f, 0.f, 0.f};

    const int ngroups = K >> 7;
    for (int g = 0; g < ngroups; ++g) {
#pragma unroll
        for (int half = 0; half < 2; ++half) {
            const int k0 = g * 128 + half * 64;
            // ---- stage A (X -> bf16 hi[/lo], swizzled) ----
            if constexpr (XMODE == 2) {
                const ushort* Xb = (const ushort*)Xv;
#pragma unroll
                for (int i = 0; i < 4; ++i) {
                    int u = t + 256 * i;
                    int m = u >> 3, ks = u & 7;
                    uint4 v = *(const uint4*)&Xb[(size_t)(m0 + m) * K + k0 + ks * 8];
                    *(uint4*)((char*)Ahi + ((m * 128 + ks * 16) ^ ((m & 7) << 4))) = v;
                }
            } else {
                const float* Xf = (const float*)Xv;
#pragma unroll
                for (int i = 0; i < 4; ++i) {
                    int u = t + 256 * i;
                    int m = u >> 3, ks = u & 7;
                    const float* src = &Xf[(size_t)(m0 + m) * K + k0 + ks * 8];
                    float4 a = *(const float4*)src;
                    float4 b = *(const float4*)(src + 4);
                    float xv[8] = {a.x, a.y, a.z, a.w, b.x, b.y, b.z, b.w};
                    ushort hv[8];
#pragma unroll
                    for (int j = 0; j < 8; ++j) hv[j] = f2bf(xv[j]);
                    uint4 hw = {pk2(hv[0], hv[1]), pk2(hv[2], hv[3]),
                                pk2(hv[4], hv[5]), pk2(hv[6], hv[7])};
                    int off = (m * 128 + ks * 16) ^ ((m & 7) << 4);
                    *(uint4*)((char*)Ahi + off) = hw;
                    if constexpr (HILO) {
                        ushort lv[8];
#pragma unroll
                        for (int j = 0; j < 8; ++j) lv[j] = f2bf(xv[j] - bf2f(hv[j]));
                        uint4 lw = {pk2(lv[0], lv[1]), pk2(lv[2], lv[3]),
                                    pk2(lv[4], lv[5]), pk2(lv[6], lv[7])};
                        *(uint4*)((char*)Alo + off) = lw;
                    }
                }
            }
            // ---- stage B (unpack nibbles - zero, EXACT bf16, [n][k] swz) ----
            const int g8 = k0 >> 3;
#pragma unroll
            for (int i = 0; i < 4; ++i) {
                int u = t + 256 * i;
                int krow = u >> 7, n = u & 127;
                uint qw = (uint)QW[(size_t)(g8 + krow) * N + n0 + n];
                int z = QZ[(size_t)g * N + n0 + n];
                ushort dv[8];
#pragma unroll
                for (int j = 0; j < 8; ++j)
                    dv[j] = f2bf((float)((int)((qw >> (4 * j)) & 15u) - z));
                uint4 dw = {pk2(dv[0], dv[1]), pk2(dv[2], dv[3]),
                            pk2(dv[4], dv[5]), pk2(dv[6], dv[7])};
                *(uint4*)((char*)Bt + ((n * 128 + krow * 16) ^ ((n & 7) << 4))) = dw;
            }
            __syncthreads();
            // ---- compute: 2 ksteps x (2 mf x 8 nf) MFMAs ----
#pragma unroll
            for (int ks = 0; ks < 2; ++ks) {
                short8v av[2], avl[2], bv[8];
#pragma unroll
                for (int mf = 0; mf < 2; ++mf) {
                    int m = w * 32 + mf * 16 + lr;
                    int off = (m * 128 + lg * 16 + ks * 64) ^ ((m & 7) << 4);
                    av[mf] = *(const short8v*)((char*)Ahi + off);
                    if constexpr (HILO) avl[mf] = *(const short8v*)((char*)Alo + off);
                }
#pragma unroll
                for (int nf = 0; nf < 8; ++nf) {
                    int n = nf * 16 + lr;
                    bv[nf] = *(const short8v*)((char*)Bt +
                              ((n * 128 + lg * 16 + ks * 64) ^ ((n & 7) << 4)));
                }
#pragma unroll
                for (int mf = 0; mf < 2; ++mf)
#pragma unroll
                    for (int nf = 0; nf < 8; ++nf) {
                        f32x4 c;
                        if (half == 0 && ks == 0) c = zc; else c = gacc[mf][nf];
                        c = __builtin_amdgcn_mfma_f32_16x16x32_bf16(av[mf], bv[nf], c, 0, 0, 0);
                        if constexpr (HILO)
                            c = __builtin_amdgcn_mfma_f32_16x16x32_bf16(avl[mf], bv[nf], c, 0, 0, 0);
                        gacc[mf][nf] = c;
                    }
            }
            __syncthreads();
        }
        // ---- per-group rescale into master accumulator ----
#pragma unroll
        for (int nf = 0; nf < 8; ++nf) {
            float sc = SC[(size_t)g * N + n0 + nf * 16 + lr];
#pragma unroll
            for (int mf = 0; mf < 2; ++mf)
#pragma unroll
                for (int r = 0; r < 4; ++r)
                    macc[mf][nf][r] += sc * gacc[mf][nf][r];
        }
    }

    // ---- epilogue ----
#pragma unroll
    for (int nf = 0; nf < 8; ++nf) {
        int col = n0 + nf * 16 + lr;
        float bv = bias ? bias[col] : 0.f;
#pragma unroll
        for (int mf = 0; mf < 2; ++mf)
#pragma unroll
            for (int r = 0; r < 4; ++r) {
                int row = m0 + w * 32 + mf * 16 + lg * 4 + r;
                float v = macc[mf][nf][r] + bv;
                if constexpr (OMODE == 0) {
                    ((float*)Yv)[(size_t)row * N + col] = v;
                } else {
                    ((ushort*)Yv)[(size_t)col * M + row] = f2bf(v);
                }
            }
    }
}

// ---------------------------------------------------------------------------
// RoPE in-place fp32 on Q [S][NH*HD] and K [S][NKV*HD]; Q also * 1/sqrt(HD).
// ---------------------------------------------------------------------------
__global__ __launch_bounds__(256) void rope_f32_kernel(
    float* __restrict__ Q, float* __restrict__ Kb,
    const float* __restrict__ cosb, const float* __restrict__ sinb)
{
    const int QP = S_LEN * NH * 64;
    const int KP = S_LEN * NKV * 64;
    int idx = blockIdx.x * 256 + threadIdx.x;
    float* buf;
    int nh, id;
    float scale;
    if (idx < QP)           { buf = Q;  nh = NH;  id = idx;      scale = 0.08838834764831845f; }
    else if (idx < QP + KP) { buf = Kb; nh = NKV; id = idx - QP; scale = 1.0f; }
    else return;
    int d  = id & 63;
    int t2 = id >> 6;
    int h  = t2 % nh;
    int s  = t2 / nh;
    float c  = cosb[s * HD + d];
    float sn = sinb[s * HD + d];
    size_t base = (size_t)s * nh * HD + h * HD + d;
    float x1 = buf[base];
    float x2 = buf[base + 64];
    buf[base]      = (x1 * c - x2 * sn) * scale;
    buf[base + 64] = (x2 * c + x1 * sn) * scale;
}

// ---------------------------------------------------------------------------
// Causal GQA flash attention, bf16 MFMA (16x16x32), compensated hi/lo QK^T.
// (unchanged from round 3 — verified, absmax 0.5)
// ---------------------------------------------------------------------------
__global__ __launch_bounds__(256) void attn_mfma_kernel(
    const float*  __restrict__ Q,    // [S][NH*HD] f32, roped, * 1/sqrt(HD)
    const float*  __restrict__ K,    // [S][NKV*HD] f32, roped
    const ushort* __restrict__ Vt,   // [NKV*HD][S] bf16 (transposed)
    ushort* __restrict__ AO)         // [S][NH*HD] bf16
{
    __shared__ ushort Khi[32 * 128];
    __shared__ ushort Klo[32 * 128];
    __shared__ ushort Vs[128 * 32];
    __shared__ ushort Ps[4][16 * 32];

    const int h  = blockIdx.x;
    const int qb = gridDim.y - 1 - blockIdx.y;
    const int s0 = qb * 64;
    const int t  = threadIdx.x;
    const int w  = t >> 6;
    const int l  = t & 63;
    const int lg = l >> 4;
    const int lr = l & 15;
    const int kvh = h >> 2;
    const int qw = s0 + w * 16;

    short8v qhi[4], qlo[4];
    {
        const float* qrow = &Q[(size_t)(qw + lr) * (NH * HD) + h * HD];
#pragma unroll
        for (int d = 0; d < 4; ++d) {
            float4 a = *(const float4*)(qrow + d * 32 + lg * 8);
            float4 b = *(const float4*)(qrow + d * 32 + lg * 8 + 4);
            float qv[8] = {a.x, a.y, a.z, a.w, b.x, b.y, b.z, b.w};
#pragma unroll
            for (int i2 = 0; i2 < 8; ++i2) {
                ushort hi = f2bf(qv[i2]);
                qhi[d][i2] = (short)hi;
                qlo[d][i2] = (short)f2bf(qv[i2] - bf2f(hi));
            }
        }
    }

    f32x4 o[8];
#pragma unroll
    for (int i = 0; i < 8; ++i) o[i] = f32x4{0.f, 0.f, 0.f, 0.f};
    float m[4], lsum[4];
#pragma unroll
    for (int r = 0; r < 4; ++r) { m[r] = -1e30f; lsum[r] = 0.f; }

    const int ntiles = qb * 2 + 2;
    for (int kt = 0; kt < ntiles; ++kt) {
        const int k0 = kt * 32;
#pragma unroll
        for (int i = 0; i < 4; ++i) {
            int e   = t + 256 * i;
            int row = e >> 5;
            int c4  = e & 31;
            float4 kv = *(const float4*)&K[(size_t)(k0 + row) * (NKV * HD) + kvh * HD + c4 * 4];
            ushort h0 = f2bf(kv.x), h1 = f2bf(kv.y), h2 = f2bf(kv.z), h3 = f2bf(kv.w);
            uint2 hw, lw;
            hw.x = pk2(h0, h1);
            hw.y = pk2(h2, h3);
            lw.x = pk2(f2bf(kv.x - bf2f(h0)), f2bf(kv.y - bf2f(h1)));
            lw.y = pk2(f2bf(kv.z - bf2f(h2)), f2bf(kv.w - bf2f(h3)));
            int off = row * 256 + ((c4 * 8) ^ ((row & 7) << 4));
            *(uint2*)((char*)Khi + off) = hw;
            *(uint2*)((char*)Klo + off) = lw;
        }
        {
            int d = t & 127, g2 = t >> 7;
            const ushort* src = &Vt[(size_t)(kvh * HD + d) * S_LEN + k0 + g2 * 16];
            uint4 v0 = *(const uint4*)src;
            uint4 v1 = *(const uint4*)(src + 8);
            char* base = (char*)Vs + d * 64;
            *(uint4*)(base + ((g2 * 32)      ^ ((d & 3) << 4))) = v0;
            *(uint4*)(base + ((g2 * 32 + 16) ^ ((d & 3) << 4))) = v1;
        }
        __syncthreads();

        if (k0 <= qw + 15) {
            f32x4 s[2];
            s[0] = f32x4{0.f, 0.f, 0.f, 0.f};
            s[1] = f32x4{0.f, 0.f, 0.f, 0.f};
#pragma unroll
            for (int d = 0; d < 4; ++d) {
#pragma unroll
                for (int nt2 = 0; nt2 < 2; ++nt2) {
                    int row = nt2 * 16 + lr;
                    int off = row * 256 + ((d * 64 + lg * 16) ^ ((row & 7) << 4));
                    short8v kh = *(const short8v*)((char*)Khi + off);
                    short8v kl = *(const short8v*)((char*)Klo + off);
                    s[nt2] = __builtin_amdgcn_mfma_f32_16x16x32_bf16(qhi[d], kh, s[nt2], 0, 0, 0);
                    s[nt2] = __builtin_amdgcn_mfma_f32_16x16x32_bf16(qlo[d], kh, s[nt2], 0, 0, 0);
                    s[nt2] = __builtin_amdgcn_mfma_f32_16x16x32_bf16(qhi[d], kl, s[nt2], 0, 0, 0);
                }
            }
            float p0a[4], p1a[4], resc[4];
#pragma unroll
            for (int r = 0; r < 4; ++r) {
                int qrow = qw + lg * 4 + r;
                float s0v = (k0 + lr      <= qrow) ? s[0][r] : -1e30f;
                float s1v = (k0 + 16 + lr <= qrow) ? s[1][r] : -1e30f;
                float mx = fmaxf(s0v, s1v);
                mx = fmaxf(mx, __shfl_xor(mx, 1));
                mx = fmaxf(mx, __shfl_xor(mx, 2));
                mx = fmaxf(mx, __shfl_xor(mx, 4));
                mx = fmaxf(mx, __shfl_xor(mx, 8));
                float mnew = fmaxf(m[r], mx);
                resc[r] = __expf(m[r] - mnew);
                m[r] = mnew;
                float p0 = __expf(s0v - mnew);
                float p1 = __expf(s1v - mnew);
                p0a[r] = p0; p1a[r] = p1;
                float ps = p0 + p1;
                ps += __shfl_xor(ps, 1);
                ps += __shfl_xor(ps, 2);
                ps += __shfl_xor(ps, 4);
                ps += __shfl_xor(ps, 8);
                lsum[r] = lsum[r] * resc[r] + ps;
            }
#pragma unroll
            for (int dt = 0; dt < 8; ++dt)
#pragma unroll
                for (int r = 0; r < 4; ++r) o[dt][r] *= resc[r];
            ushort* pw = Ps[w];
#pragma unroll
            for (int r = 0; r < 4; ++r) {
                int row = lg * 4 + r;
                *(ushort*)((char*)pw + row * 64 + (((lr)      * 2) ^ ((row & 3) << 4))) = f2bf(p0a[r]);
                *(ushort*)((char*)pw + row * 64 + (((lr + 16) * 2) ^ ((row & 3) << 4))) = f2bf(p1a[r]);
            }
            asm volatile("s_waitcnt lgkmcnt(0)" ::: "memory");
            short8v pf = *(const short8v*)((char*)pw + lr * 64 + ((lg * 16) ^ ((lr & 3) << 4)));
#pragma unroll
            for (int dt = 0; dt < 8; ++dt) {
                int dim = dt * 16 + lr;
                short8v vf = *(const short8v*)((char*)Vs + dim * 64 + ((lg * 16) ^ ((dim & 3) << 4)));
                o[dt] = __builtin_amdgcn_mfma_f32_16x16x32_bf16(pf, vf, o[dt], 0, 0, 0);
            }
        }
        __syncthreads();
    }

#pragma unroll
    for (int r = 0; r < 4; ++r) {
        float inv = 1.f / lsum[r];
        int qrow = qw + lg * 4 + r;
        ushort* dst = &AO[(size_t)qrow * (NH * HD) + h * HD];
#pragma unroll
        for (int dt = 0; dt < 8; ++dt) dst[dt * 16 + lr] = f2bf(o[dt][r] * inv);
    }
}

// ---------------------------------------------------------------------------
extern "C" void kernel_launch(void* const* d_in, const int* in_sizes, int n_in,
                              void* d_out, int out_size, void* d_ws, size_t ws_size,
                              hipStream_t stream)
{
    const float* x    = (const float*)d_in[0];
    const float* cosb = (const float*)d_in[1];
    const float* sinb = (const float*)d_in[2];
    const float* q_sc = (const float*)d_in[3];
    const float* q_b  = (const float*)d_in[4];
    const float* k_sc = (const float*)d_in[5];
    const float* k_b  = (const float*)d_in[6];
    const float* v_sc = (const float*)d_in[7];
    const float* v_b  = (const float*)d_in[8];
    const float* o_sc = (const float*)d_in[9];
    const int* q_qw   = (const int*)d_in[10];
    const int* q_qz   = (const int*)d_in[11];
    const int* k_qw   = (const int*)d_in[12];
    const int* k_qz   = (const int*)d_in[13];
    const int* v_qw   = (const int*)d_in[14];
    const int* v_qz   = (const int*)d_in[15];
    const int* o_qw   = (const int*)d_in[16];
    const int* o_qz   = (const int*)d_in[17];
    float* out = (float*)d_out;

    // ws: Qf32 32MB | Kf32 8MB | VbfT 4MB | AObf16 16MB  = 60MB
    char* ws = (char*)d_ws;
    float*  Qf   = (float*)ws;
    float*  Kf   = (float*)(ws + (size_t)32 * 1024 * 1024);
    ushort* VbfT = (ushort*)(ws + (size_t)40 * 1024 * 1024);
    ushort* AObf = (ushort*)(ws + (size_t)44 * 1024 * 1024);

    // projections: MFMA fused-dequant GEMMs
    qgemm_mfma_kernel<0, 0><<<dim3(NH * HD / 128, S_LEN / 128), 256, 0, stream>>>(
        x, q_qw, q_sc, q_qz, q_b, Qf, S_LEN, HIDDEN, NH * HD);
    qgemm_mfma_kernel<0, 0><<<dim3(NKV * HD / 128, S_LEN / 128), 256, 0, stream>>>(
        x, k_qw, k_sc, k_qz, k_b, Kf, S_LEN, HIDDEN, NKV * HD);
    qgemm_mfma_kernel<1, 2><<<dim3(NKV * HD / 128, S_LEN / 128), 256, 0, stream>>>(
        x, v_qw, v_sc, v_qz, v_b, VbfT, S_LEN, HIDDEN, NKV * HD);

    rope_f32_kernel<<<(S_LEN * NH * 64 + S_LEN * NKV * 64) / 256, 256, 0, stream>>>(
        Qf, Kf, cosb, sinb);

    attn_mfma_kernel<<<dim3(NH, S_LEN / 64), 256, 0, stream>>>(Qf, Kf, VbfT, AObf);

    qgemm_mfma_kernel<2, 0><<<dim3(HIDDEN / 128, S_LEN / 128), 256, 0, stream>>>(
        AObf, o_qw, o_sc, o_qz, nullptr, out, S_LEN, NH * HD, HIDDEN);
}